// Round 4
// baseline (325.766 us; speedup 1.0000x reference)
//
#include <hip/hip_runtime.h>

// Problem constants
constexpr int TB = 16;        // batch
constexpr int NP = 2048;      // pre neurons
constexpr int NQ = 2048;      // post neurons
constexpr int TT = 256;       // timesteps
constexpr int KH = TB * TT;   // 4096, half-K
constexpr int KT = 2 * KH;    // 8192, total contraction length

typedef unsigned short ushort_t;
typedef __attribute__((ext_vector_type(8))) __bf16 bf16x8;
typedef __attribute__((ext_vector_type(4))) float f32x4;

__device__ __forceinline__ ushort_t f2bf(float f) {
    unsigned u = __builtin_bit_cast(unsigned, f);
    u = (u + 0x7FFFu + ((u >> 16) & 1u)) >> 16;   // RNE, inputs finite
    return (ushort_t)u;
}

union Pack16 { ushort_t u[16]; uint4 v[2]; };

// Decay powers (constexpr chains; ~1e-6 rel err, far below bf16 rounding)
constexpr float DF1 = 0.95122942450071400910f;            // exp(-0.05)
constexpr float DF2 = DF1 * DF1;
constexpr float DF4 = DF2 * DF2;
constexpr float DF8 = DF4 * DF4;
constexpr float DF16 = DF8 * DF8;
constexpr float DF32 = DF16 * DF16;
constexpr float DF64 = DF32 * DF32;
constexpr float DF128 = DF64 * DF64;

constexpr float DX1 = 0.99014786386058731819f;            // exp(-1/101)
constexpr float DX2 = DX1 * DX1;
constexpr float DX4 = DX2 * DX2;
constexpr float DX8 = DX4 * DX4;
constexpr float DX16 = DX8 * DX8;
constexpr float DX32 = DX16 * DX16;
constexpr float DX64 = DX32 * DX32;
constexpr float DX128 = DX64 * DX64;

template <int K>
__device__ __forceinline__ float seg_step(float b, float pw, int sl) {
    float t = __shfl_up(b, K, 64);
    return (sl >= K) ? fmaf(pw, t, b) : b;
}

// ---------------------------------------------------------------------------
// Stage 1: 16 lanes per (b, neuron) row; lane owns timesteps sl*16..sl*16+15.
// Local affine fold -> 4-step segmented scan -> serial expand. (unchanged)
// ---------------------------------------------------------------------------
__global__ __launch_bounds__(256) void stage_traces(
    const float* __restrict__ pre, const float* __restrict__ post,
    const float* __restrict__ mApP, const float* __restrict__ mAmP,
    ushort_t* __restrict__ Ab, ushort_t* __restrict__ Bb,
    float* __restrict__ partials)
{
    const int tid  = threadIdx.x;
    const int lane = tid & 63;
    const int wv   = tid >> 6;
    const int sl   = lane & 15;       // segment lane (time chunk)
    const int seg  = lane >> 4;       // row within wave
    const int rowg = blockIdx.x * 16 + wv * 4 + seg;   // 0..65535
    const bool isPre = rowg < TB * NP;                 // block-uniform
    const int m = isPre ? rowg : rowg - TB * NP;       // b*2048 + neuron
    const int b = m >> 11;
    const int r = m & 2047;

    const float4* src = (const float4*)((isPre ? pre : post) + (size_t)m * TT);
    float f[16];
    #pragma unroll
    for (int j = 0; j < 4; ++j) {
        float4 u = src[sl * 4 + j];
        f[4 * j] = u.x; f[4 * j + 1] = u.y; f[4 * j + 2] = u.z; f[4 * j + 3] = u.w;
    }
    float cnt = 0.f;
    #pragma unroll
    for (int j = 0; j < 16; ++j) cnt += f[j];

    // ---- fast-decay trace (x_pre for pre rows, x_post for post rows) ----
    float Cf = 0.f;
    #pragma unroll
    for (int j = 0; j < 16; ++j) Cf = DF1 * (Cf + f[j]);
    float bs = Cf;
    bs = seg_step<1>(bs, DF16, sl);
    bs = seg_step<2>(bs, DF32, sl);
    bs = seg_step<4>(bs, DF64, sl);
    bs = seg_step<8>(bs, DF128, sl);
    float xinf = __shfl_up(bs, 1, 64);
    if (sl == 0) xinf = 0.f;

    float xf[16];
    {
        float x = xinf;
        #pragma unroll
        for (int j = 0; j < 16; ++j) { xf[j] = x; x = DF1 * (x + f[j]); }
    }

    Pack16 pa, pb;
    if (isPre) {
        #pragma unroll
        for (int j = 0; j < 16; ++j) {
            pa.u[j] = f2bf(xf[j]);
            pb.u[j] = (f[j] != 0.f) ? 0x3F80u : 0u;
        }
    } else {
        float Cx = 0.f;
        #pragma unroll
        for (int j = 0; j < 16; ++j) Cx = DX1 * (Cx + f[j]);
        float bx = Cx;
        bx = seg_step<1>(bx, DX16, sl);
        bx = seg_step<2>(bx, DX32, sl);
        bx = seg_step<4>(bx, DX64, sl);
        bx = seg_step<8>(bx, DX128, sl);
        float xint = __shfl_up(bx, 1, 64);
        if (sl == 0) xint = 0.f;

        const float Ap = *mApP;
        const float Am = *mAmP;
        float xt = xint;
        #pragma unroll
        for (int j = 0; j < 16; ++j) {
            pa.u[j] = (f[j] != 0.f) ? f2bf(fmaf(0.0065f, xt, Ap)) : 0u;
            pb.u[j] = f2bf(-Am * xf[j]);
            xt = DX1 * (xt + f[j]);
        }
    }

    ushort_t* o0 = (isPre ? Ab : Bb) + (size_t)r * KT + b * TT + sl * 16;
    *(uint4*)o0       = pa.v[0];
    *(uint4*)(o0 + 8) = pa.v[1];
    *(uint4*)(o0 + KH)     = pb.v[0];
    *(uint4*)(o0 + KH + 8) = pb.v[1];

    #pragma unroll
    for (int off = 32; off > 0; off >>= 1)
        cnt += __shfl_down(cnt, off, 64);
    __shared__ float wsum[4];
    if (lane == 0) wsum[wv] = cnt;
    __syncthreads();
    if (tid == 0) {
        float s = (wsum[0] + wsum[1]) + (wsum[2] + wsum[3]);
        atomicAdd(&partials[(blockIdx.x & 63) * 16], s);  // 64 slots, 64B apart
    }
}

// ---------------------------------------------------------------------------
// Stage 2: split-K GEMM, double-buffered prefetch, UNROLLED x2 K-loop with
// incremental global pointers (VALU cut), and FUSED epilogue: per-tile flag;
// second-arriving z-half reads the other's partial + W, scales, clips, writes
// Out. z=0 partial goes to d_out (overwritten by the final), z=1 to ws.
// ---------------------------------------------------------------------------
__device__ __forceinline__ void async16(const ushort_t* g, ushort_t* l) {
    __builtin_amdgcn_global_load_lds(
        (const __attribute__((address_space(1))) unsigned int*)g,
        (__attribute__((address_space(3))) unsigned int*)l,
        16, 0, 0);
}

__global__ __launch_bounds__(256, 2) void gemm_fused(
    const ushort_t* __restrict__ Ab, const ushort_t* __restrict__ Bb,
    const float* __restrict__ W, const float* __restrict__ partials,
    int* __restrict__ flags, float* __restrict__ P0, float* __restrict__ P1,
    float* __restrict__ Out)
{
    __shared__ ushort_t As[2][128 * 64];
    __shared__ ushort_t Bs[2][128 * 64];

    const int tid  = threadIdx.x;
    const int lane = tid & 63;
    const int wv   = tid >> 6;
    const int wr   = wv >> 1;
    const int wc   = wv & 1;
    const int quad = lane >> 4;
    const int m16  = lane & 15;

    const int p0 = blockIdx.y * 128;
    const int q0 = blockIdx.x * 128;
    const int kbase = blockIdx.z * (KT / 2);
    const int ldsbase = wv * 512;           // elements; wave-uniform

    // hoisted staging pointers, advanced +64 elements per stage call
    const ushort_t* gaP[4];
    const ushort_t* gbP[4];
    #pragma unroll
    for (int rr = 0; rr < 4; ++rr) {
        const int c   = rr * 256 + tid;
        const int row = c >> 3;
        const int kk8 = (c & 7) ^ (row & 7);
        gaP[rr] = Ab + (size_t)(p0 + row) * KT + kbase + kk8 * 8;
        gbP[rr] = Bb + (size_t)(q0 + row) * KT + kbase + kk8 * 8;
    }

    f32x4 acc[4][4] = {};

    auto stageF = [&](int buf) {
        #pragma unroll
        for (int rr = 0; rr < 4; ++rr) {
            async16(gaP[rr], &As[buf][rr * 2048 + ldsbase]);
            async16(gbP[rr], &Bs[buf][rr * 2048 + ldsbase]);
            gaP[rr] += 64;
            gbP[rr] += 64;
        }
    };
    auto computeF = [&](int buf) {
        #pragma unroll
        for (int ks = 0; ks < 2; ++ks) {
            bf16x8 af[4], bf[4];
            #pragma unroll
            for (int i = 0; i < 4; ++i) {
                const int row  = wr * 64 + i * 16 + m16;
                const int slot = (ks * 4 + quad) ^ (row & 7);
                af[i] = *(const bf16x8*)&As[buf][row * 64 + slot * 8];
            }
            #pragma unroll
            for (int j = 0; j < 4; ++j) {
                const int row  = wc * 64 + j * 16 + m16;
                const int slot = (ks * 4 + quad) ^ (row & 7);
                bf[j] = *(const bf16x8*)&Bs[buf][row * 64 + slot * 8];
            }
            #pragma unroll
            for (int i = 0; i < 4; ++i)
                #pragma unroll
                for (int j = 0; j < 4; ++j)
                    acc[i][j] = __builtin_amdgcn_mfma_f32_16x16x32_bf16(
                        af[i], bf[j], acc[i][j], 0, 0, 0);
        }
    };

    constexpr int NIT = (KT / 2) / 64;   // 64 k-chunks, 32 double-iters
    stageF(0);
    for (int kt2 = 0; kt2 < NIT / 2; ++kt2) {
        __syncthreads();                   // chunk 2*kt2 landed; buf1 reads done
        stageF(1);                         // prefetch chunk 2*kt2+1
        computeF(0);
        __syncthreads();                   // chunk 2*kt2+1 landed; buf0 reads done
        if (kt2 + 1 < NIT / 2)
            stageF(0);                     // prefetch chunk 2*kt2+2
        computeF(1);
    }

    // ---- publish partial ----
    float* Pmine = blockIdx.z ? P1 : P0;
    #pragma unroll
    for (int i = 0; i < 4; ++i) {
        const int prow = p0 + wr * 64 + i * 16 + quad * 4;
        #pragma unroll
        for (int j = 0; j < 4; ++j) {
            const int qcol = q0 + wc * 64 + j * 16 + m16;
            #pragma unroll
            for (int r2 = 0; r2 < 4; ++r2)
                Pmine[(size_t)(prow + r2) * NQ + qcol] = acc[i][j][r2];
        }
    }

    __threadfence();                       // release: partial visible device-wide
    __syncthreads();
    __shared__ int s_old;
    if (tid == 0)
        s_old = atomicAdd(&flags[blockIdx.y * 16 + blockIdx.x], 1);
    __syncthreads();
    if (s_old != 1) return;                // first arriver: done

    __threadfence();                       // acquire: see other block's partial
    const float* Pother = blockIdx.z ? P0 : P1;

    // scale from spike-count partials (exact integers); butterfly -> all lanes
    float v = partials[lane * 16];
    #pragma unroll
    for (int off = 32; off > 0; off >>= 1)
        v += __shfl_xor(v, off, 64);
    const float scale = sqrtf(0.1f / (v * (1.0f / 4096.0f) + 1e-6f));

    #pragma unroll
    for (int i = 0; i < 4; ++i) {
        const int prow = p0 + wr * 64 + i * 16 + quad * 4;
        #pragma unroll
        for (int j = 0; j < 4; ++j) {
            const int qcol = q0 + wc * 64 + j * 16 + m16;
            #pragma unroll
            for (int r2 = 0; r2 < 4; ++r2) {
                const size_t idx = (size_t)(prow + r2) * NQ + qcol;
                float o = fmaf(scale, acc[i][j][r2] + Pother[idx], W[idx]);
                o = fminf(fmaxf(o, -2.f), 2.f);
                Out[idx] = o;
            }
        }
    }
}

extern "C" void kernel_launch(void* const* d_in, const int* in_sizes, int n_in,
                              void* d_out, int out_size, void* d_ws, size_t ws_size,
                              hipStream_t stream) {
    const float* pre  = (const float*)d_in[0];
    const float* post = (const float*)d_in[1];
    const float* W    = (const float*)d_in[2];
    const float* mAp  = (const float*)d_in[3];
    const float* mAm  = (const float*)d_in[4];
    float* out = (float*)d_out;

    char* ws = (char*)d_ws;
    float* partials = (float*)ws;                                    // 64 slots, 64B apart
    int* flags      = (int*)(ws + 16384);                            // 256 tile flags
    ushort_t* Ab = (ushort_t*)(ws + 32768);                          // 33.6 MB
    ushort_t* Bb = (ushort_t*)(ws + 32768 + (size_t)NP * KT * 2);    // 33.6 MB
    float* P1    = (float*)(ws + 32768 + 2 * (size_t)NP * KT * 2);   // 16.8 MB

    hipMemsetAsync(ws, 0, 32768, stream);   // zero partials + flags

    stage_traces<<<dim3((TB * NP + TB * NQ) / 16), dim3(256), 0, stream>>>(
        pre, post, mAp, mAm, Ab, Bb, partials);

    gemm_fused<<<dim3(NQ / 128, NP / 128, 2), dim3(256), 0, stream>>>(
        Ab, Bb, W, partials, flags, out, P1, out);
}

// Round 5
// 208.649 us; speedup vs baseline: 1.5613x; 1.5613x over previous
//
#include <hip/hip_runtime.h>

// Problem constants
constexpr int TB = 16;        // batch
constexpr int NP = 2048;      // pre neurons
constexpr int NQ = 2048;      // post neurons
constexpr int TT = 256;       // timesteps
constexpr int KH = TB * TT;   // 4096, half-K
constexpr int KT = 2 * KH;    // 8192, total contraction length

typedef unsigned short ushort_t;
typedef __attribute__((ext_vector_type(8))) __bf16 bf16x8;
typedef __attribute__((ext_vector_type(4))) float f32x4;

__device__ __forceinline__ ushort_t f2bf(float f) {
    unsigned u = __builtin_bit_cast(unsigned, f);
    u = (u + 0x7FFFu + ((u >> 16) & 1u)) >> 16;   // RNE, inputs finite
    return (ushort_t)u;
}

union Pack16 { ushort_t u[16]; uint4 v[2]; };

// Decay powers (constexpr chains; ~1e-6 rel err, far below bf16 rounding)
constexpr float DF1 = 0.95122942450071400910f;            // exp(-0.05)
constexpr float DF2 = DF1 * DF1;
constexpr float DF4 = DF2 * DF2;
constexpr float DF8 = DF4 * DF4;
constexpr float DF16 = DF8 * DF8;
constexpr float DF32 = DF16 * DF16;
constexpr float DF64 = DF32 * DF32;
constexpr float DF128 = DF64 * DF64;

constexpr float DX1 = 0.99014786386058731819f;            // exp(-1/101)
constexpr float DX2 = DX1 * DX1;
constexpr float DX4 = DX2 * DX2;
constexpr float DX8 = DX4 * DX4;
constexpr float DX16 = DX8 * DX8;
constexpr float DX32 = DX16 * DX16;
constexpr float DX64 = DX32 * DX32;
constexpr float DX128 = DX64 * DX64;

template <int K>
__device__ __forceinline__ float seg_step(float b, float pw, int sl) {
    float t = __shfl_up(b, K, 64);
    return (sl >= K) ? fmaf(pw, t, b) : b;
}

// ---------------------------------------------------------------------------
// Stage 1: 16 lanes per (b, neuron) row; lane owns timesteps sl*16..sl*16+15.
// Local affine fold -> 4-step segmented scan -> serial expand.
// __launch_bounds__(256, 1): lift register cap — r2 showed VGPR_Count=12,
// suspected compiler spill-to-scratch under default occupancy heuristic.
// ---------------------------------------------------------------------------
__global__ __launch_bounds__(256, 1) void stage_traces(
    const float* __restrict__ pre, const float* __restrict__ post,
    const float* __restrict__ mApP, const float* __restrict__ mAmP,
    ushort_t* __restrict__ Ab, ushort_t* __restrict__ Bb,
    float* __restrict__ partials)
{
    const int tid  = threadIdx.x;
    const int lane = tid & 63;
    const int wv   = tid >> 6;
    const int sl   = lane & 15;       // segment lane (time chunk)
    const int seg  = lane >> 4;       // row within wave
    const int rowg = blockIdx.x * 16 + wv * 4 + seg;   // 0..65535
    const bool isPre = rowg < TB * NP;                 // block-uniform
    const int m = isPre ? rowg : rowg - TB * NP;       // b*2048 + neuron
    const int b = m >> 11;
    const int r = m & 2047;

    const float4* src = (const float4*)((isPre ? pre : post) + (size_t)m * TT);
    float f[16];
    #pragma unroll
    for (int j = 0; j < 4; ++j) {
        float4 u = src[sl * 4 + j];
        f[4 * j] = u.x; f[4 * j + 1] = u.y; f[4 * j + 2] = u.z; f[4 * j + 3] = u.w;
    }
    float cnt = 0.f;
    #pragma unroll
    for (int j = 0; j < 16; ++j) cnt += f[j];

    // ---- fast-decay trace (x_pre for pre rows, x_post for post rows) ----
    float Cf = 0.f;
    #pragma unroll
    for (int j = 0; j < 16; ++j) Cf = DF1 * (Cf + f[j]);
    float bs = Cf;
    bs = seg_step<1>(bs, DF16, sl);
    bs = seg_step<2>(bs, DF32, sl);
    bs = seg_step<4>(bs, DF64, sl);
    bs = seg_step<8>(bs, DF128, sl);
    float xinf = __shfl_up(bs, 1, 64);
    if (sl == 0) xinf = 0.f;

    float xf[16];
    {
        float x = xinf;
        #pragma unroll
        for (int j = 0; j < 16; ++j) { xf[j] = x; x = DF1 * (x + f[j]); }
    }

    Pack16 pa, pb;
    if (isPre) {
        #pragma unroll
        for (int j = 0; j < 16; ++j) {
            pa.u[j] = f2bf(xf[j]);
            pb.u[j] = (f[j] != 0.f) ? 0x3F80u : 0u;
        }
    } else {
        float Cx = 0.f;
        #pragma unroll
        for (int j = 0; j < 16; ++j) Cx = DX1 * (Cx + f[j]);
        float bx = Cx;
        bx = seg_step<1>(bx, DX16, sl);
        bx = seg_step<2>(bx, DX32, sl);
        bx = seg_step<4>(bx, DX64, sl);
        bx = seg_step<8>(bx, DX128, sl);
        float xint = __shfl_up(bx, 1, 64);
        if (sl == 0) xint = 0.f;

        const float Ap = *mApP;
        const float Am = *mAmP;
        float xt = xint;
        #pragma unroll
        for (int j = 0; j < 16; ++j) {
            pa.u[j] = (f[j] != 0.f) ? f2bf(fmaf(0.0065f, xt, Ap)) : 0u;
            pb.u[j] = f2bf(-Am * xf[j]);
            xt = DX1 * (xt + f[j]);
        }
    }

    ushort_t* o0 = (isPre ? Ab : Bb) + (size_t)r * KT + b * TT + sl * 16;
    *(uint4*)o0       = pa.v[0];
    *(uint4*)(o0 + 8) = pa.v[1];
    *(uint4*)(o0 + KH)     = pb.v[0];
    *(uint4*)(o0 + KH + 8) = pb.v[1];

    #pragma unroll
    for (int off = 32; off > 0; off >>= 1)
        cnt += __shfl_down(cnt, off, 64);
    __shared__ float wsum[4];
    if (lane == 0) wsum[wv] = cnt;
    __syncthreads();
    if (tid == 0) {
        float s = (wsum[0] + wsum[1]) + (wsum[2] + wsum[3]);
        atomicAdd(&partials[(blockIdx.x & 63) * 16], s);  // 64 slots, 64B apart
    }
}

// ---------------------------------------------------------------------------
// Stage 2: split-K GEMM, double-buffered prefetch, unrolled x2 K-loop with
// hoisted incremental global pointers (r4's proven VALU cut). Publishes raw
// fp32 partials: z=0 -> d_out, z=1 -> ws. NO fused epilogue (r4 regression:
// per-block device fences + cross-XCD partial reads cost ~126 us tail).
// ---------------------------------------------------------------------------
__device__ __forceinline__ void async16(const ushort_t* g, ushort_t* l) {
    __builtin_amdgcn_global_load_lds(
        (const __attribute__((address_space(1))) unsigned int*)g,
        (__attribute__((address_space(3))) unsigned int*)l,
        16, 0, 0);
}

__global__ __launch_bounds__(256, 2) void gemm_split(
    const ushort_t* __restrict__ Ab, const ushort_t* __restrict__ Bb,
    float* __restrict__ P0, float* __restrict__ P1)
{
    __shared__ ushort_t As[2][128 * 64];
    __shared__ ushort_t Bs[2][128 * 64];

    const int tid  = threadIdx.x;
    const int lane = tid & 63;
    const int wv   = tid >> 6;
    const int wr   = wv >> 1;
    const int wc   = wv & 1;
    const int quad = lane >> 4;
    const int m16  = lane & 15;

    const int p0 = blockIdx.y * 128;
    const int q0 = blockIdx.x * 128;
    const int kbase = blockIdx.z * (KT / 2);
    const int ldsbase = wv * 512;           // elements; wave-uniform

    // hoisted staging pointers, advanced +64 elements per stage call
    const ushort_t* gaP[4];
    const ushort_t* gbP[4];
    #pragma unroll
    for (int rr = 0; rr < 4; ++rr) {
        const int c   = rr * 256 + tid;
        const int row = c >> 3;
        const int kk8 = (c & 7) ^ (row & 7);
        gaP[rr] = Ab + (size_t)(p0 + row) * KT + kbase + kk8 * 8;
        gbP[rr] = Bb + (size_t)(q0 + row) * KT + kbase + kk8 * 8;
    }

    f32x4 acc[4][4] = {};

    auto stageF = [&](int buf) {
        #pragma unroll
        for (int rr = 0; rr < 4; ++rr) {
            async16(gaP[rr], &As[buf][rr * 2048 + ldsbase]);
            async16(gbP[rr], &Bs[buf][rr * 2048 + ldsbase]);
            gaP[rr] += 64;
            gbP[rr] += 64;
        }
    };
    auto computeF = [&](int buf) {
        #pragma unroll
        for (int ks = 0; ks < 2; ++ks) {
            bf16x8 af[4], bf[4];
            #pragma unroll
            for (int i = 0; i < 4; ++i) {
                const int row  = wr * 64 + i * 16 + m16;
                const int slot = (ks * 4 + quad) ^ (row & 7);
                af[i] = *(const bf16x8*)&As[buf][row * 64 + slot * 8];
            }
            #pragma unroll
            for (int j = 0; j < 4; ++j) {
                const int row  = wc * 64 + j * 16 + m16;
                const int slot = (ks * 4 + quad) ^ (row & 7);
                bf[j] = *(const bf16x8*)&Bs[buf][row * 64 + slot * 8];
            }
            #pragma unroll
            for (int i = 0; i < 4; ++i)
                #pragma unroll
                for (int j = 0; j < 4; ++j)
                    acc[i][j] = __builtin_amdgcn_mfma_f32_16x16x32_bf16(
                        af[i], bf[j], acc[i][j], 0, 0, 0);
        }
    };

    constexpr int NIT = (KT / 2) / 64;   // 64 k-chunks, 32 double-iters
    stageF(0);
    for (int kt2 = 0; kt2 < NIT / 2; ++kt2) {
        __syncthreads();                   // even chunk landed; buf1 reads done
        stageF(1);                         // prefetch odd chunk
        computeF(0);
        __syncthreads();                   // odd chunk landed; buf0 reads done
        if (kt2 + 1 < NIT / 2)
            stageF(0);                     // prefetch next even chunk
        computeF(1);
    }

    float* P = blockIdx.z ? P1 : P0;
    #pragma unroll
    for (int i = 0; i < 4; ++i) {
        const int prow = p0 + wr * 64 + i * 16 + quad * 4;
        #pragma unroll
        for (int j = 0; j < 4; ++j) {
            const int qcol = q0 + wc * 64 + j * 16 + m16;
            #pragma unroll
            for (int r2 = 0; r2 < 4; ++r2)
                P[(size_t)(prow + r2) * NQ + qcol] = acc[i][j][r2];
        }
    }
}

// ---------------------------------------------------------------------------
// Stage 3: Out = clip(W + scale*(P0+P1), -2, 2); P0 lives in d_out (in-place).
// ---------------------------------------------------------------------------
__global__ __launch_bounds__(256) void merge_out(
    const float* __restrict__ W, const float* __restrict__ P1,
    const float* __restrict__ partials, float* __restrict__ Out)
{
    __shared__ float s_scale;
    const int tid = threadIdx.x;
    if (tid < 64) {
        float v = partials[tid * 16];
        #pragma unroll
        for (int off = 32; off > 0; off >>= 1)
            v += __shfl_down(v, off, 64);
        if (tid == 0)
            s_scale = sqrtf(0.1f / (v * (1.0f / 4096.0f) + 1e-6f));
    }
    __syncthreads();
    const float scale = s_scale;

    const size_t i4 = (size_t)blockIdx.x * 256 + tid;
    float4 w = ((const float4*)W)[i4];
    float4 a = ((const float4*)Out)[i4];
    float4 c = ((const float4*)P1)[i4];
    float4 o;
    o.x = fminf(fmaxf(fmaf(scale, a.x + c.x, w.x), -2.f), 2.f);
    o.y = fminf(fmaxf(fmaf(scale, a.y + c.y, w.y), -2.f), 2.f);
    o.z = fminf(fmaxf(fmaf(scale, a.z + c.z, w.z), -2.f), 2.f);
    o.w = fminf(fmaxf(fmaf(scale, a.w + c.w, w.w), -2.f), 2.f);
    ((float4*)Out)[i4] = o;
}

extern "C" void kernel_launch(void* const* d_in, const int* in_sizes, int n_in,
                              void* d_out, int out_size, void* d_ws, size_t ws_size,
                              hipStream_t stream) {
    const float* pre  = (const float*)d_in[0];
    const float* post = (const float*)d_in[1];
    const float* W    = (const float*)d_in[2];
    const float* mAp  = (const float*)d_in[3];
    const float* mAm  = (const float*)d_in[4];
    float* out = (float*)d_out;

    char* ws = (char*)d_ws;
    float* partials = (float*)ws;                                    // 64 slots, 64B apart
    ushort_t* Ab = (ushort_t*)(ws + 16384);                          // 33.6 MB
    ushort_t* Bb = (ushort_t*)(ws + 16384 + (size_t)NP * KT * 2);    // 33.6 MB
    float* P1    = (float*)(ws + 16384 + 2 * (size_t)NP * KT * 2);   // 16.8 MB

    hipMemsetAsync(partials, 0, 64 * 16 * sizeof(float), stream);

    stage_traces<<<dim3((TB * NP + TB * NQ) / 16), dim3(256), 0, stream>>>(
        pre, post, mAp, mAm, Ab, Bb, partials);

    gemm_split<<<dim3(NQ / 128, NP / 128, 2), dim3(256), 0, stream>>>(
        Ab, Bb, out, P1);

    merge_out<<<dim3(NP * NQ / 1024), dim3(256), 0, stream>>>(
        W, P1, partials, out);
}

// Round 6
// 205.869 us; speedup vs baseline: 1.5824x; 1.0135x over previous
//
#include <hip/hip_runtime.h>

// Problem constants
constexpr int TB = 16;        // batch
constexpr int NP = 2048;      // pre neurons
constexpr int NQ = 2048;      // post neurons
constexpr int TT = 256;       // timesteps
constexpr int KH = TB * TT;   // 4096, half-K
constexpr int KT = 2 * KH;    // 8192, total contraction length

typedef unsigned short ushort_t;
typedef __attribute__((ext_vector_type(8))) __bf16 bf16x8;
typedef __attribute__((ext_vector_type(4))) float f32x4;

// bf16 round-to-nearest-even, as uint (inputs finite)
__device__ __forceinline__ unsigned bf1(float f) {
    unsigned u = __builtin_bit_cast(unsigned, f);
    return (u + 0x7FFFu + ((u >> 16) & 1u)) >> 16;
}
__device__ __forceinline__ unsigned pack2(float lo, float hi) {
    return bf1(lo) | (bf1(hi) << 16);
}
__device__ __forceinline__ unsigned spk2(float a, float b) {
    return ((a != 0.f) ? 0x3F80u : 0u) | ((b != 0.f) ? 0x3F800000u : 0u);
}

// Decay powers (constexpr chains; ~1e-6 rel err, far below bf16 rounding)
constexpr float DF1 = 0.95122942450071400910f;            // exp(-0.05)
constexpr float DF2 = DF1 * DF1;
constexpr float DF4 = DF2 * DF2;
constexpr float DF8 = DF4 * DF4;
constexpr float DF16 = DF8 * DF8;
constexpr float DF32 = DF16 * DF16;
constexpr float DF64 = DF32 * DF32;
constexpr float DF128 = DF64 * DF64;

constexpr float DX1 = 0.99014786386058731819f;            // exp(-1/101)
constexpr float DX2 = DX1 * DX1;
constexpr float DX4 = DX2 * DX2;
constexpr float DX8 = DX4 * DX4;
constexpr float DX16 = DX8 * DX8;
constexpr float DX32 = DX16 * DX16;
constexpr float DX64 = DX32 * DX32;
constexpr float DX128 = DX64 * DX64;

template <int K>
__device__ __forceinline__ float seg_step(float b, float pw, int sl) {
    float t = __shfl_up(b, K, 64);
    return (sl >= K) ? fmaf(pw, t, b) : b;
}

__device__ __forceinline__ float fold4(float C, float4 u, float d) {
    C = d * (C + u.x); C = d * (C + u.y); C = d * (C + u.z); C = d * (C + u.w);
    return C;
}
// trace values used at each of 4 steps; advances x past them
__device__ __forceinline__ float4 expand4(float& x, float4 u, float d) {
    float4 t;
    t.x = x; x = d * (x + u.x);
    t.y = x; x = d * (x + u.y);
    t.z = x; x = d * (x + u.z);
    t.w = x; x = d * (x + u.w);
    return t;
}

// ---------------------------------------------------------------------------
// Stage 1: 16 lanes per (b, neuron) row; lane owns timesteps sl*16..sl*16+15.
// Local affine fold -> 4-step segmented scan -> serial expand.
// NO unions / indexed private arrays (r2-r5 versions had VGPR_Count=12 =>
// private aggregates lowered to scratch; every pack was an HBM round-trip).
// All state is named scalars/float4/uint4 -> pure registers.
// ---------------------------------------------------------------------------
__global__ __launch_bounds__(256) void stage_traces(
    const float* __restrict__ pre, const float* __restrict__ post,
    const float* __restrict__ mApP, const float* __restrict__ mAmP,
    ushort_t* __restrict__ Ab, ushort_t* __restrict__ Bb,
    float* __restrict__ partials)
{
    const int tid  = threadIdx.x;
    const int lane = tid & 63;
    const int wv   = tid >> 6;
    const int sl   = lane & 15;       // segment lane (time chunk)
    const int seg  = lane >> 4;       // row within wave
    const int rowg = blockIdx.x * 16 + wv * 4 + seg;   // 0..65535
    const bool isPre = rowg < TB * NP;                 // block-uniform
    const int m = isPre ? rowg : rowg - TB * NP;       // b*2048 + neuron
    const int b = m >> 11;
    const int r = m & 2047;

    const float4* src =
        (const float4*)((isPre ? pre : post) + (size_t)m * TT) + sl * 4;
    const float4 u0 = src[0], u1 = src[1], u2 = src[2], u3 = src[3];

    float cnt = ((u0.x + u0.y) + (u0.z + u0.w)) + ((u1.x + u1.y) + (u1.z + u1.w))
              + ((u2.x + u2.y) + (u2.z + u2.w)) + ((u3.x + u3.y) + (u3.z + u3.w));

    // ---- fast-decay trace carry (x_pre for pre rows, x_post for post) ----
    float Cf = fold4(fold4(fold4(fold4(0.f, u0, DF1), u1, DF1), u2, DF1), u3, DF1);
    float bs = Cf;
    bs = seg_step<1>(bs, DF16, sl);
    bs = seg_step<2>(bs, DF32, sl);
    bs = seg_step<4>(bs, DF64, sl);
    bs = seg_step<8>(bs, DF128, sl);
    float xinf = __shfl_up(bs, 1, 64);
    if (sl == 0) xinf = 0.f;

    // expand fast trace over the 16 owned steps
    float xm = xinf;
    const float4 t0 = expand4(xm, u0, DF1);
    const float4 t1 = expand4(xm, u1, DF1);
    const float4 t2 = expand4(xm, u2, DF1);
    const float4 t3 = expand4(xm, u3, DF1);

    uint4 va, va2, vb, vb2;
    if (isPre) {
        va  = uint4{pack2(t0.x, t0.y), pack2(t0.z, t0.w),
                    pack2(t1.x, t1.y), pack2(t1.z, t1.w)};
        va2 = uint4{pack2(t2.x, t2.y), pack2(t2.z, t2.w),
                    pack2(t3.x, t3.y), pack2(t3.z, t3.w)};
        vb  = uint4{spk2(u0.x, u0.y), spk2(u0.z, u0.w),
                    spk2(u1.x, u1.y), spk2(u1.z, u1.w)};
        vb2 = uint4{spk2(u2.x, u2.y), spk2(u2.z, u2.w),
                    spk2(u3.x, u3.y), spk2(u3.z, u3.w)};
    } else {
        // slow (triplet) trace carry + expand
        float Cx = fold4(fold4(fold4(fold4(0.f, u0, DX1), u1, DX1), u2, DX1), u3, DX1);
        float bx = Cx;
        bx = seg_step<1>(bx, DX16, sl);
        bx = seg_step<2>(bx, DX32, sl);
        bx = seg_step<4>(bx, DX64, sl);
        bx = seg_step<8>(bx, DX128, sl);
        float xint = __shfl_up(bx, 1, 64);
        if (sl == 0) xint = 0.f;

        float xt = xint;
        const float4 w0 = expand4(xt, u0, DX1);
        const float4 w1 = expand4(xt, u1, DX1);
        const float4 w2 = expand4(xt, u2, DX1);
        const float4 w3 = expand4(xt, u3, DX1);

        const float Ap = *mApP;
        const float Am = *mAmP;
        auto av2 = [&](float sa, float ta, float sb, float tb) -> unsigned {
            unsigned lo = (sa != 0.f) ? bf1(fmaf(0.0065f, ta, Ap)) : 0u;
            unsigned hi = (sb != 0.f) ? bf1(fmaf(0.0065f, tb, Ap)) : 0u;
            return lo | (hi << 16);
        };
        va  = uint4{av2(u0.x, w0.x, u0.y, w0.y), av2(u0.z, w0.z, u0.w, w0.w),
                    av2(u1.x, w1.x, u1.y, w1.y), av2(u1.z, w1.z, u1.w, w1.w)};
        va2 = uint4{av2(u2.x, w2.x, u2.y, w2.y), av2(u2.z, w2.z, u2.w, w2.w),
                    av2(u3.x, w3.x, u3.y, w3.y), av2(u3.z, w3.z, u3.w, w3.w)};
        vb  = uint4{pack2(-Am * t0.x, -Am * t0.y), pack2(-Am * t0.z, -Am * t0.w),
                    pack2(-Am * t1.x, -Am * t1.y), pack2(-Am * t1.z, -Am * t1.w)};
        vb2 = uint4{pack2(-Am * t2.x, -Am * t2.y), pack2(-Am * t2.z, -Am * t2.w),
                    pack2(-Am * t3.x, -Am * t3.y), pack2(-Am * t3.z, -Am * t3.w)};
    }

    ushort_t* o0 = (isPre ? Ab : Bb) + (size_t)r * KT + b * TT + sl * 16;
    ((uint4*)o0)[0] = va;
    ((uint4*)o0)[1] = va2;
    ((uint4*)(o0 + KH))[0] = vb;
    ((uint4*)(o0 + KH))[1] = vb2;

    #pragma unroll
    for (int off = 32; off > 0; off >>= 1)
        cnt += __shfl_down(cnt, off, 64);
    __shared__ float wsum[4];
    if (lane == 0) wsum[wv] = cnt;
    __syncthreads();
    if (tid == 0) {
        float s = (wsum[0] + wsum[1]) + (wsum[2] + wsum[3]);
        atomicAdd(&partials[(blockIdx.x & 63) * 16], s);  // 64 slots, 64B apart
    }
}

// ---------------------------------------------------------------------------
// Stage 2: split-K GEMM, double-buffered prefetch, unrolled x2 K-loop,
// hoisted incremental global pointers. XCD-aware 1D-grid swizzle: each XCD
// (id&7, round-robin dispatch) owns a 4x8 patch of (p,q) tiles per z-half,
// bounding the co-resident L2 working set (~12 MB/XCD vs unbounded).
// Publishes raw fp32 partials: z=0 -> d_out, z=1 -> ws.
// ---------------------------------------------------------------------------
__device__ __forceinline__ void async16(const ushort_t* g, ushort_t* l) {
    __builtin_amdgcn_global_load_lds(
        (const __attribute__((address_space(1))) unsigned int*)g,
        (__attribute__((address_space(3))) unsigned int*)l,
        16, 0, 0);
}

__global__ __launch_bounds__(256, 2) void gemm_split(
    const ushort_t* __restrict__ Ab, const ushort_t* __restrict__ Bb,
    float* __restrict__ P0, float* __restrict__ P1)
{
    __shared__ ushort_t As[2][128 * 64];
    __shared__ ushort_t Bs[2][128 * 64];

    const int tid  = threadIdx.x;
    const int lane = tid & 63;
    const int wv   = tid >> 6;
    const int wr   = wv >> 1;
    const int wc   = wv & 1;
    const int quad = lane >> 4;
    const int m16  = lane & 15;

    // XCD swizzle: id&7 = XCD (round-robin). XCD x -> rows 4*(x>>1)+, cols 8*(x&1)+
    const int id  = blockIdx.x;
    const int xcd = id & 7;
    const int j5  = id >> 3;          // 0..63
    const int z   = j5 & 1;
    const int t   = j5 >> 1;          // 0..31
    const int pt  = ((xcd >> 1) << 2) + (t >> 3);   // 0..15
    const int qt  = ((xcd & 1) << 3) + (t & 7);     // 0..15

    const int p0 = pt * 128;
    const int q0 = qt * 128;
    const int kbase = z * (KT / 2);
    const int ldsbase = wv * 512;           // elements; wave-uniform

    // hoisted staging pointers, advanced +64 elements per stage call
    const ushort_t* gaP[4];
    const ushort_t* gbP[4];
    #pragma unroll
    for (int rr = 0; rr < 4; ++rr) {
        const int c   = rr * 256 + tid;
        const int row = c >> 3;
        const int kk8 = (c & 7) ^ (row & 7);
        gaP[rr] = Ab + (size_t)(p0 + row) * KT + kbase + kk8 * 8;
        gbP[rr] = Bb + (size_t)(q0 + row) * KT + kbase + kk8 * 8;
    }

    f32x4 acc[4][4] = {};

    auto stageF = [&](int buf) {
        #pragma unroll
        for (int rr = 0; rr < 4; ++rr) {
            async16(gaP[rr], &As[buf][rr * 2048 + ldsbase]);
            async16(gbP[rr], &Bs[buf][rr * 2048 + ldsbase]);
            gaP[rr] += 64;
            gbP[rr] += 64;
        }
    };
    auto computeF = [&](int buf) {
        #pragma unroll
        for (int ks = 0; ks < 2; ++ks) {
            bf16x8 af[4], bf[4];
            #pragma unroll
            for (int i = 0; i < 4; ++i) {
                const int row  = wr * 64 + i * 16 + m16;
                const int slot = (ks * 4 + quad) ^ (row & 7);
                af[i] = *(const bf16x8*)&As[buf][row * 64 + slot * 8];
            }
            #pragma unroll
            for (int jj = 0; jj < 4; ++jj) {
                const int row  = wc * 64 + jj * 16 + m16;
                const int slot = (ks * 4 + quad) ^ (row & 7);
                bf[jj] = *(const bf16x8*)&Bs[buf][row * 64 + slot * 8];
            }
            #pragma unroll
            for (int i = 0; i < 4; ++i)
                #pragma unroll
                for (int jj = 0; jj < 4; ++jj)
                    acc[i][jj] = __builtin_amdgcn_mfma_f32_16x16x32_bf16(
                        af[i], bf[jj], acc[i][jj], 0, 0, 0);
        }
    };

    constexpr int NIT = (KT / 2) / 64;   // 64 k-chunks, 32 double-iters
    stageF(0);
    for (int kt2 = 0; kt2 < NIT / 2; ++kt2) {
        __syncthreads();                   // even chunk landed; buf1 reads done
        stageF(1);                         // prefetch odd chunk
        computeF(0);
        __syncthreads();                   // odd chunk landed; buf0 reads done
        if (kt2 + 1 < NIT / 2)
            stageF(0);                     // prefetch next even chunk
        computeF(1);
    }

    float* P = z ? P1 : P0;
    #pragma unroll
    for (int i = 0; i < 4; ++i) {
        const int prow = p0 + wr * 64 + i * 16 + quad * 4;
        #pragma unroll
        for (int jj = 0; jj < 4; ++jj) {
            const int qcol = q0 + wc * 64 + jj * 16 + m16;
            #pragma unroll
            for (int r2 = 0; r2 < 4; ++r2)
                P[(size_t)(prow + r2) * NQ + qcol] = acc[i][jj][r2];
        }
    }
}

// ---------------------------------------------------------------------------
// Stage 3: Out = clip(W + scale*(P0+P1), -2, 2); P0 lives in d_out (in-place).
// ---------------------------------------------------------------------------
__global__ __launch_bounds__(256) void merge_out(
    const float* __restrict__ W, const float* __restrict__ P1,
    const float* __restrict__ partials, float* __restrict__ Out)
{
    __shared__ float s_scale;
    const int tid = threadIdx.x;
    if (tid < 64) {
        float v = partials[tid * 16];
        #pragma unroll
        for (int off = 32; off > 0; off >>= 1)
            v += __shfl_down(v, off, 64);
        if (tid == 0)
            s_scale = sqrtf(0.1f / (v * (1.0f / 4096.0f) + 1e-6f));
    }
    __syncthreads();
    const float scale = s_scale;

    const size_t i4 = (size_t)blockIdx.x * 256 + tid;
    float4 w = ((const float4*)W)[i4];
    float4 a = ((const float4*)Out)[i4];
    float4 c = ((const float4*)P1)[i4];
    float4 o;
    o.x = fminf(fmaxf(fmaf(scale, a.x + c.x, w.x), -2.f), 2.f);
    o.y = fminf(fmaxf(fmaf(scale, a.y + c.y, w.y), -2.f), 2.f);
    o.z = fminf(fmaxf(fmaf(scale, a.z + c.z, w.z), -2.f), 2.f);
    o.w = fminf(fmaxf(fmaf(scale, a.w + c.w, w.w), -2.f), 2.f);
    ((float4*)Out)[i4] = o;
}

extern "C" void kernel_launch(void* const* d_in, const int* in_sizes, int n_in,
                              void* d_out, int out_size, void* d_ws, size_t ws_size,
                              hipStream_t stream) {
    const float* pre  = (const float*)d_in[0];
    const float* post = (const float*)d_in[1];
    const float* W    = (const float*)d_in[2];
    const float* mAp  = (const float*)d_in[3];
    const float* mAm  = (const float*)d_in[4];
    float* out = (float*)d_out;

    char* ws = (char*)d_ws;
    float* partials = (float*)ws;                                    // 64 slots, 64B apart
    ushort_t* Ab = (ushort_t*)(ws + 16384);                          // 33.6 MB
    ushort_t* Bb = (ushort_t*)(ws + 16384 + (size_t)NP * KT * 2);    // 33.6 MB
    float* P1    = (float*)(ws + 16384 + 2 * (size_t)NP * KT * 2);   // 16.8 MB

    hipMemsetAsync(partials, 0, 64 * 16 * sizeof(float), stream);

    stage_traces<<<dim3((TB * NP + TB * NQ) / 16), dim3(256), 0, stream>>>(
        pre, post, mAp, mAm, Ab, Bb, partials);

    gemm_split<<<dim3(512), dim3(256), 0, stream>>>(Ab, Bb, out, P1);

    merge_out<<<dim3(NP * NQ / 1024), dim3(256), 0, stream>>>(
        W, P1, partials, out);
}